// Round 17
// baseline (408.754 us; speedup 1.0000x reference)
//
#include <hip/hip_runtime.h>
#include <stdint.h>

#define D_FEAT   128
#define TOPK     128
#define KSPLIT   128           // h-only GEMM; key err < 1 bin, fixed by exact window
#define SCALE    4096.0f
#define SCALE2   16777216.0f   // SCALE^2 (2^24, exact)
#define SEL_CAP  8192          // per-query candidate capacity
#define SAMPLE_N 1024
#define SAMPLE_R 24

typedef float    f32x4 __attribute__((ext_vector_type(4)));
typedef _Float16 half8 __attribute__((ext_vector_type(8)));

// ---------------- fused prep: sqnorm + f16 hi-part, grid-stride ----------------
__global__ __launch_bounds__(256) void prep_kernel(
        const float* __restrict__ Q, const float* __restrict__ Dta,
        unsigned short* __restrict__ Asp, unsigned short* __restrict__ Bsp,
        float* __restrict__ x2, float* __restrict__ y2, int nQ, int nD) {
    const int lane = threadIdx.x & 63;
    const int total = nQ + nD;
    for (int wid = blockIdx.x * 4 + (threadIdx.x >> 6); wid < total; wid += gridDim.x * 4) {
        const float* src; unsigned short* dst; float* nrm; int row;
        if (wid < nQ) { row = wid; src = Q; dst = Asp; nrm = x2; }
        else          { row = wid - nQ; src = Dta; dst = Bsp; nrm = y2; }
        float a0 = src[(size_t)row * D_FEAT + lane];
        float a1 = src[(size_t)row * D_FEAT + 64 + lane];
        float s = a0 * a0 + a1 * a1;
        #pragma unroll
        for (int off = 32; off > 0; off >>= 1) s += __shfl_down(s, off, 64);
        if (lane == 0) nrm[row] = s;

        size_t b = (size_t)row * KSPLIT;
        #pragma unroll
        for (int e = 0; e < 2; ++e) {
            _Float16 h = (_Float16)((e == 0 ? a0 : a1) * SCALE);
            unsigned short hu;
            __builtin_memcpy(&hu, &h, 2);
            dst[b + lane + e * 64] = hu;
        }
    }
}

// ---------------- MFMA distance kernel (128x256, 2-buf, grid-stride persistent) ----------------
#define BM 128
#define BN 256
#define BKS 32
#define NSLAB (KSPLIT / BKS)   // 4
#define ASLOT (BM * 4)         // 512 16B-slots
#define BSLOT (BN * 4)         // 1024 16B-slots
#define BUFELEM ((ASLOT + BSLOT) * 8)   // u16 per buffer (12288 = 24 KB)

static __device__ __forceinline__ half8 lds_read_half8(const unsigned short* p) {
    half8 r;
    __builtin_memcpy(&r, p, 16);
    return r;
}

static __device__ __forceinline__ void gload_lds16(const unsigned short* g, unsigned short* l) {
    __builtin_amdgcn_global_load_lds(
        (const __attribute__((address_space(1))) unsigned int*)g,
        (__attribute__((address_space(3))) unsigned int*)l, 16, 0, 0);
}

static __device__ __forceinline__ void stage_slab(
        const unsigned short* __restrict__ Asp,
        const unsigned short* __restrict__ Bsp,
        unsigned short* buf, int aRowBase, int bRowBase, int kt, int w, int l) {
    {   // A: 512 slots, one wave-round
        int slot = w * 64 + l;
        int row = slot >> 2, c = slot & 3;
        int sc  = c ^ ((row >> 1) & 3);
        gload_lds16(Asp + (size_t)(aRowBase + row) * KSPLIT + kt + sc * 8,
                    buf + (size_t)(w * 64) * 8);
    }
    #pragma unroll
    for (int r = 0; r < 2; ++r) {   // B: 1024 slots, two wave-rounds
        int slot = r * 512 + w * 64 + l;
        int row = slot >> 2, c = slot & 3;
        int sc  = c ^ ((row >> 1) & 3);
        gload_lds16(Bsp + (size_t)(bRowBase + row) * KSPLIT + kt + sc * 8,
                    buf + ASLOT * 8 + (size_t)(r * 512 + w * 64) * 8);
    }
}

template<int MODE>
__global__ __launch_bounds__(512, 4) void dist_mfma_kernel(
        const unsigned short* __restrict__ Asp,   // [n][128]
        const unsigned short* __restrict__ Bsp,   // [N][128]
        const float* __restrict__ x2,
        const float* __restrict__ y2,
        unsigned short* __restrict__ keyout,      // MODE 0: [n][N]
        const unsigned int* __restrict__ Tq,      // MODE 1
        unsigned int* __restrict__ cnt,           // MODE 1
        unsigned int* __restrict__ candbuf,      // MODE 1
        int N, int rowsM) {
    __shared__ __align__(16) unsigned short sh[2 * BUFELEM];   // 48 KB
    unsigned short* bufA = sh;
    unsigned short* bufB = sh + BUFELEM;

    const int nwg = (N / BN) * rowsM;
    const int cpx = nwg >> 3;
    const int tid  = threadIdx.x;
    const int lane = tid & 63;
    const int w    = tid >> 6;
    const int wr   = w >> 2, wc = w & 3;   // 2 x 4 wave grid, 64x64 per wave
    const int c    = lane >> 4;

    for (int vbid = blockIdx.x; vbid < nwg; vbid += gridDim.x) {
        // XCD swizzle: vbid&7 constant per block (stride 1024) -> stays in one XCD band
        const int swz = (vbid & 7) * cpx + (vbid >> 3);
        const int col   = swz / rowsM;
        const int mrowi = swz - col * rowsM;
        const int nb = col * BN;
        const int mb = mrowi * BM;

        f32x4 acc[4][4];
        #pragma unroll
        for (int i = 0; i < 4; ++i)
            #pragma unroll
            for (int j = 0; j < 4; ++j)
                acc[i][j] = (f32x4){0.f, 0.f, 0.f, 0.f};

        stage_slab(Asp, Bsp, bufA, mb, nb, 0, w, lane);

        #pragma unroll
        for (int s = 0; s < NSLAB; ++s) {
            __syncthreads();                   // drains stage(s) + compute(s-1) done
            unsigned short* cur = (s & 1) ? bufB : bufA;
            unsigned short* nxt = (s & 1) ? bufA : bufB;
            if (s + 1 < NSLAB)
                stage_slab(Asp, Bsp, nxt, mb, nb, (s + 1) * BKS, w, lane);  // DMA overlaps MFMA
            const unsigned short* Acur = cur;
            const unsigned short* Bcur = cur + ASLOT * 8;
            half8 af[4], bf[4];
            #pragma unroll
            for (int f = 0; f < 4; ++f) {
                int m  = wr * 64 + f * 16 + (lane & 15);
                af[f] = lds_read_half8(Acur + (size_t)(m * 4 + (c ^ ((m >> 1) & 3))) * 8);
                int nn = wc * 64 + f * 16 + (lane & 15);
                bf[f] = lds_read_half8(Bcur + (size_t)(nn * 4 + (c ^ ((nn >> 1) & 3))) * 8);
            }
            __builtin_amdgcn_s_setprio(1);
            #pragma unroll
            for (int i = 0; i < 4; ++i)
                #pragma unroll
                for (int j = 0; j < 4; ++j)
                    acc[i][j] = __builtin_amdgcn_mfma_f32_16x16x32_f16(af[i], bf[j], acc[i][j], 0, 0, 0);
            __builtin_amdgcn_s_setprio(0);
        }

        __syncthreads();    // all LDS reads done before epilogue reuse

        float x2v[16];
        unsigned int Trow[16];
        #pragma unroll
        for (int fi = 0; fi < 4; ++fi)
            #pragma unroll
            for (int r = 0; r < 4; ++r) {
                int ml = wr * 64 + fi * 16 + (lane >> 4) * 4 + r;
                x2v[fi * 4 + r] = x2[mb + ml];
                if (MODE == 1) Trow[fi * 4 + r] = Tq[mb + ml] + 4u;   // window completeness
            }

        if (MODE == 0) {
            #pragma unroll
            for (int fj = 0; fj < 4; ++fj) {
                float yv = y2[nb + wc * 64 + fj * 16 + (lane & 15)];
                #pragma unroll
                for (int fi = 0; fi < 4; ++fi) {
                    #pragma unroll
                    for (int r = 0; r < 4; ++r) {
                        float d = fmaf(-2.0f, acc[fi][fj][r], SCALE2 * (x2v[fi * 4 + r] + yv));
                        d = fmaxf(d, 0.0f);
                        int m  = mb + wr * 64 + fi * 16 + (lane >> 4) * 4 + r;
                        int nn = nb + wc * 64 + fj * 16 + (lane & 15);
                        keyout[(size_t)m * N + nn] = (unsigned short)(__float_as_uint(d) >> 15);
                    }
                }
            }
        } else {
            unsigned int* rowcnt  = (unsigned int*)sh;             // 128
            unsigned int* slots   = rowcnt + 128;                  // 128*32
            unsigned int* rowbase = slots + 128 * 32;              // 128
            for (int i = tid; i < 128; i += 512) rowcnt[i] = 0;
            __syncthreads();
            #pragma unroll
            for (int fj = 0; fj < 4; ++fj) {
                float yv = y2[nb + wc * 64 + fj * 16 + (lane & 15)];
                #pragma unroll
                for (int fi = 0; fi < 4; ++fi) {
                    #pragma unroll
                    for (int r = 0; r < 4; ++r) {
                        float d = fmaf(-2.0f, acc[fi][fj][r], SCALE2 * (x2v[fi * 4 + r] + yv));
                        d = fmaxf(d, 0.0f);
                        unsigned int key = __float_as_uint(d) >> 15;
                        if (key < Trow[fi * 4 + r]) {
                            int ml = wr * 64 + fi * 16 + (lane >> 4) * 4 + r;
                            int cl = wc * 64 + fj * 16 + (lane & 15);     // 0..255
                            unsigned int p = atomicAdd(&rowcnt[ml], 1u);
                            if (p < 32) {
                                slots[ml * 32 + p] = (key << 16) | (unsigned int)cl;
                            } else {   // rare spill: direct global append
                                unsigned int b = atomicAdd(&cnt[mb + ml], 1u);
                                if (b < SEL_CAP)
                                    candbuf[(size_t)(mb + ml) * SEL_CAP + b] =
                                        (key << 16) | (unsigned int)(nb + cl);
                            }
                        }
                    }
                }
            }
            __syncthreads();
            int ml2 = tid >> 2;                  // 512 threads -> 4 per row
            unsigned int cc = rowcnt[ml2]; if (cc > 32) cc = 32;
            if ((tid & 3) == 0) rowbase[ml2] = atomicAdd(&cnt[mb + ml2], cc);
            __syncthreads();
            unsigned int bse = rowbase[ml2];
            for (unsigned int i = tid & 3; i < cc; i += 4) {
                unsigned int e = slots[ml2 * 32 + i];
                unsigned int dst = bse + i;
                if (dst < SEL_CAP)
                    candbuf[(size_t)(mb + ml2) * SEL_CAP + dst] =
                        (e & 0xFFFF0000u) | (unsigned int)(nb + (e & 0xFFu));
            }
        }
        __syncthreads();    // protect sh (epilogue/staging) before next tile's DMA
    }
}

// ---------------- per-query threshold from sample keys (also zeroes cnt) ----------------
__global__ __launch_bounds__(256) void tsel_kernel(const unsigned short* __restrict__ skey,
                                                   unsigned int* __restrict__ Tq,
                                                   unsigned int* __restrict__ cnt) {
    __shared__ unsigned int hist[256];
    __shared__ unsigned int binsel, cumsel, losel;
    const int tid = threadIdx.x;
    const int q   = blockIdx.x;
    if (tid == 0) cnt[q] = 0;
    uint2 v = ((const uint2*)(skey + (size_t)q * SAMPLE_N))[tid];   // 4 keys
    unsigned int k0 = v.x & 0xFFFFu, k1 = v.x >> 16;
    unsigned int k2 = v.y & 0xFFFFu, k3 = v.y >> 16;

    hist[tid] = 0;
    __syncthreads();
    atomicAdd(&hist[k0 >> 8], 1u); atomicAdd(&hist[k1 >> 8], 1u);
    atomicAdd(&hist[k2 >> 8], 1u); atomicAdd(&hist[k3 >> 8], 1u);
    __syncthreads();
    if (tid == 0) {
        unsigned int cum = 0;
        for (int b = 0; b < 256; ++b) {
            unsigned int h = hist[b];
            if (cum + h >= SAMPLE_R) { binsel = (unsigned int)b; cumsel = cum; break; }
            cum += h;
        }
    }
    __syncthreads();
    unsigned int bsel = binsel, need = SAMPLE_R - cumsel;
    hist[tid] = 0;
    __syncthreads();
    if ((k0 >> 8) == bsel) atomicAdd(&hist[k0 & 0xFFu], 1u);
    if ((k1 >> 8) == bsel) atomicAdd(&hist[k1 & 0xFFu], 1u);
    if ((k2 >> 8) == bsel) atomicAdd(&hist[k2 & 0xFFu], 1u);
    if ((k3 >> 8) == bsel) atomicAdd(&hist[k3 & 0xFFu], 1u);
    __syncthreads();
    if (tid == 0) {
        unsigned int cum = 0;
        for (int b = 0; b < 256; ++b) {
            cum += hist[b];
            if (cum >= need) { losel = (unsigned int)b; break; }
        }
        Tq[q] = ((bsel << 8) | losel) + 1u;
    }
}

// ---------------- selection + vote (v10): shfl 3-probe tau + wave-parallel f64 window ----------------
#define SEL_T3  512
#define NW      (SEL_T3 / 64)       // 8 waves
#define TIE_CAP 1024

__global__ __launch_bounds__(SEL_T3, 4) void select10_kernel(
        const unsigned int* __restrict__ cnt,
        const unsigned int* __restrict__ candbuf,
        const float* __restrict__ labels,
        const float* __restrict__ Q, const float* __restrict__ Dta,
        int* __restrict__ out, int n_total, int out_size) {
    __shared__ unsigned int cand[SEL_CAP];    // 32 KB
    __shared__ double       cval[TIE_CAP];    // 8 KB
    __shared__ unsigned int ckey[TIE_CAP];    // 4 KB
    __shared__ unsigned int red[2][3][NW];
    __shared__ unsigned int votes_sh, tcnt, base_sh;

    const int tid  = threadIdx.x;
    const int lane = tid & 63;
    const int wid  = tid >> 6;
    const int q    = blockIdx.x;

    unsigned int mraw = cnt[q];
    const int m = (int)(mraw < SEL_CAP ? mraw : SEL_CAP);
    for (int i = tid; i < m; i += SEL_T3) cand[i] = candbuf[(size_t)q * SEL_CAP + i];
    if (tid == 0) { votes_sh = 0; tcnt = 0; base_sh = 0; }
    __syncthreads();

    // ---- 8-pass 3-probe binary search for tau (key16 of the 128th smallest) ----
    uint32_t lo = 0, hi = 65536;
    #pragma unroll 1
    for (int pass = 0; pass < 8; ++pass) {
        uint32_t qs = (hi - lo) >> 2;
        uint32_t p1 = lo + qs, p2 = p1 + qs, p3 = p2 + qs;
        uint32_t c1 = 0, c2 = 0, c3 = 0;
        #pragma unroll
        for (int p = 0; p < SEL_CAP / SEL_T3; ++p) {
            int idx = p * SEL_T3 + tid;
            if (idx < m) {
                uint32_t k = cand[idx] >> 16;
                c1 += (k < p1); c2 += (k < p2); c3 += (k < p3);
            }
        }
        #pragma unroll
        for (int off = 32; off > 0; off >>= 1) {
            c1 += __shfl_down(c1, off, 64);
            c2 += __shfl_down(c2, off, 64);
            c3 += __shfl_down(c3, off, 64);
        }
        int bsel = pass & 1;
        if (lane == 0) {
            red[bsel][0][wid] = c1; red[bsel][1][wid] = c2; red[bsel][2][wid] = c3;
        }
        __syncthreads();
        uint32_t t1 = 0, t2 = 0, t3 = 0;
        #pragma unroll
        for (int ww = 0; ww < NW; ++ww) {
            t1 += red[bsel][0][ww]; t2 += red[bsel][1][ww]; t3 += red[bsel][2][ww];
        }
        if      (t1 >= TOPK) { hi = p1; }
        else if (t2 >= TOPK) { lo = p1; hi = p2; }
        else if (t3 >= TOPK) { lo = p2; hi = p3; }
        else                 { lo = p3; }
    }
    const int tau = (int)lo;
    int wlo = tau - 3; if (wlo < 0) wlo = 0;    // certain only outside [tau-3, tau+2]
    const int whi = tau + 2;

    // ---- pass: votes + base below window; gather window entries (index+label) ----
    unsigned int votes = 0, basec = 0;
    for (int i = tid; i < m; i += SEL_T3) {
        unsigned int u = cand[i];
        int          k = (int)(u >> 16);
        unsigned int j = u & 0xFFFFu;
        if (k < wlo) {
            basec++;
            votes += (labels[j] > 0.5f) ? 1u : 0u;
        } else if (k <= whi) {
            unsigned int lab = (labels[j] > 0.5f) ? 0x80000000u : 0u;
            unsigned int e = atomicAdd(&tcnt, 1u);
            if (e < TIE_CAP) ckey[e] = j | lab;
        }
    }
    #pragma unroll
    for (int off = 32; off > 0; off >>= 1) {
        votes += __shfl_down(votes, off, 64);
        basec += __shfl_down(basec, off, 64);
    }
    if (lane == 0) {
        if (votes) atomicAdd(&votes_sh, votes);
        if (basec) atomicAdd(&base_sh, basec);
    }
    __syncthreads();

    // ---- wave-parallel exact f64 distances for window entries ----
    unsigned int mt = tcnt; if (mt > TIE_CAP) mt = TIE_CAP;
    const float* qp = Q + (size_t)q * D_FEAT;
    for (unsigned int e = wid; e < mt; e += NW) {
        unsigned int j = ckey[e] & 0xFFFFu;
        const float* dp = Dta + (size_t)j * D_FEAT;
        double s = 0.0;
        #pragma unroll
        for (int k2 = 0; k2 < 2; ++k2) {
            int idx = lane + k2 * 64;
            double df = (double)qp[idx] - (double)dp[idx];
            s = fma(df, df, s);
        }
        #pragma unroll
        for (int off = 32; off > 0; off >>= 1) s += __shfl_down(s, off, 64);
        if (lane == 0) cval[e] = s;
    }
    __syncthreads();

    // ---- exact ranking of window; take first t_take ----
    const unsigned int t_take = TOPK - base_sh;    // base < 128 by tau construction
    for (unsigned int e = tid; e < mt; e += SEL_T3) {
        double       ve = cval[e];
        unsigned int ke = ckey[e];
        unsigned int ie = ke & 0x7FFFFFFFu;
        unsigned int rank = 0;
        for (unsigned int f = 0; f < mt; ++f) {
            double       vf = cval[f];
            unsigned int jf = ckey[f] & 0x7FFFFFFFu;
            rank += (vf < ve || (vf == ve && jf < ie)) ? 1u : 0u;
        }
        if (rank < t_take && (ke & 0x80000000u)) atomicAdd(&votes_sh, 1u);
    }
    __syncthreads();

    if (tid == 0) {
        out[q] = (votes_sh > TOPK / 2) ? 1 : 0;     // 64/64 tie -> class 0
        if (q == 0 && out_size > n_total) out[n_total] = 0;
    }
}

// ---------------- host ----------------
extern "C" void kernel_launch(void* const* d_in, const int* in_sizes, int n_in,
                              void* d_out, int out_size, void* d_ws, size_t ws_size,
                              hipStream_t stream) {
    const float* Q   = (const float*)d_in[0];
    const float* Dta = (const float*)d_in[1];
    const float* L   = (const float*)d_in[2];
    const int n = in_sizes[0] / D_FEAT;    // 2048
    const int N = in_sizes[1] / D_FEAT;    // 65536
    int* out = (int*)d_out;

    char* ws = (char*)d_ws;
    size_t off = 0;
    float* y2 = (float*)(ws + off);          off += (((size_t)N * 4) + 255) & ~(size_t)255;
    float* x2 = (float*)(ws + off);          off += (((size_t)n * 4) + 255) & ~(size_t)255;
    unsigned short* Asp = (unsigned short*)(ws + off); off += (((size_t)n * KSPLIT * 2) + 255) & ~(size_t)255;
    unsigned short* Bsp = (unsigned short*)(ws + off); off += (((size_t)N * KSPLIT * 2) + 255) & ~(size_t)255;
    unsigned short* skey = (unsigned short*)(ws + off); off += (((size_t)n * SAMPLE_N * 2) + 255) & ~(size_t)255;
    unsigned int* Tq  = (unsigned int*)(ws + off);    off += (((size_t)n * 4) + 255) & ~(size_t)255;
    unsigned int* cnt = (unsigned int*)(ws + off);    off += (((size_t)n * 4) + 255) & ~(size_t)255;
    unsigned int* candbuf = (unsigned int*)(ws + off);   // n * SEL_CAP * 4 = 64 MB

    // fused sqnorm + h-split, grid-stride
    prep_kernel<<<dim3(2048), dim3(256), 0, stream>>>(Q, Dta, Asp, Bsp, x2, y2, n, N);

    const int rowsM = n / BM;                         // 16
    dist_mfma_kernel<0><<<dim3((SAMPLE_N / BN) * rowsM), dim3(512), 0, stream>>>(
        Asp, Bsp, x2, y2, skey, nullptr, nullptr, nullptr, SAMPLE_N, rowsM);
    tsel_kernel<<<dim3(n), dim3(256), 0, stream>>>(skey, Tq, cnt);
    // persistent grid-stride: 1024 blocks x ~8 tiles each
    dist_mfma_kernel<1><<<dim3(1024), dim3(512), 0, stream>>>(
        Asp, Bsp, x2, y2, nullptr, Tq, cnt, candbuf, N, rowsM);
    select10_kernel<<<dim3(n), dim3(SEL_T3), 0, stream>>>(cnt, candbuf, L, Q, Dta, out, n, out_size);
}

// Round 18
// 232.462 us; speedup vs baseline: 1.7584x; 1.7584x over previous
//
#include <hip/hip_runtime.h>
#include <stdint.h>

#define D_FEAT   128
#define TOPK     128
#define KSPLIT   128           // h-only GEMM; key err < 1 bin, fixed by exact window
#define SCALE    4096.0f
#define SCALE2   16777216.0f   // SCALE^2 (2^24, exact)
#define SEL_CAP  8192          // per-query candidate capacity
#define SAMPLE_N 1024
#define SAMPLE_R 24

typedef float    f32x4 __attribute__((ext_vector_type(4)));
typedef _Float16 half8 __attribute__((ext_vector_type(8)));

// ---------------- fused prep: sqnorm + f16 hi-part, grid-stride ----------------
__global__ __launch_bounds__(256) void prep_kernel(
        const float* __restrict__ Q, const float* __restrict__ Dta,
        unsigned short* __restrict__ Asp, unsigned short* __restrict__ Bsp,
        float* __restrict__ x2, float* __restrict__ y2, int nQ, int nD) {
    const int lane = threadIdx.x & 63;
    const int total = nQ + nD;
    for (int wid = blockIdx.x * 4 + (threadIdx.x >> 6); wid < total; wid += gridDim.x * 4) {
        const float* src; unsigned short* dst; float* nrm; int row;
        if (wid < nQ) { row = wid; src = Q; dst = Asp; nrm = x2; }
        else          { row = wid - nQ; src = Dta; dst = Bsp; nrm = y2; }
        float a0 = src[(size_t)row * D_FEAT + lane];
        float a1 = src[(size_t)row * D_FEAT + 64 + lane];
        float s = a0 * a0 + a1 * a1;
        #pragma unroll
        for (int off = 32; off > 0; off >>= 1) s += __shfl_down(s, off, 64);
        if (lane == 0) nrm[row] = s;

        size_t b = (size_t)row * KSPLIT;
        #pragma unroll
        for (int e = 0; e < 2; ++e) {
            _Float16 h = (_Float16)((e == 0 ? a0 : a1) * SCALE);
            unsigned short hu;
            __builtin_memcpy(&hu, &h, 2);
            dst[b + lane + e * 64] = hu;
        }
    }
}

// ---------------- MFMA distance kernel (128x256 tile, 2-buf, K=128) ----------------
#define BM 128
#define BN 256
#define BKS 32
#define NSLAB (KSPLIT / BKS)   // 4
#define ASLOT (BM * 4)         // 512 16B-slots
#define BSLOT (BN * 4)         // 1024 16B-slots
#define BUFELEM ((ASLOT + BSLOT) * 8)   // u16 per buffer (12288 = 24 KB)

static __device__ __forceinline__ half8 lds_read_half8(const unsigned short* p) {
    half8 r;
    __builtin_memcpy(&r, p, 16);
    return r;
}

static __device__ __forceinline__ void gload_lds16(const unsigned short* g, unsigned short* l) {
    __builtin_amdgcn_global_load_lds(
        (const __attribute__((address_space(1))) unsigned int*)g,
        (__attribute__((address_space(3))) unsigned int*)l, 16, 0, 0);
}

static __device__ __forceinline__ void stage_slab(
        const unsigned short* __restrict__ Asp,
        const unsigned short* __restrict__ Bsp,
        unsigned short* buf, int aRowBase, int bRowBase, int kt, int w, int l) {
    {   // A: 512 slots, one wave-round
        int slot = w * 64 + l;
        int row = slot >> 2, c = slot & 3;
        int sc  = c ^ ((row >> 1) & 3);
        gload_lds16(Asp + (size_t)(aRowBase + row) * KSPLIT + kt + sc * 8,
                    buf + (size_t)(w * 64) * 8);
    }
    #pragma unroll
    for (int r = 0; r < 2; ++r) {   // B: 1024 slots, two wave-rounds
        int slot = r * 512 + w * 64 + l;
        int row = slot >> 2, c = slot & 3;
        int sc  = c ^ ((row >> 1) & 3);
        gload_lds16(Bsp + (size_t)(bRowBase + row) * KSPLIT + kt + sc * 8,
                    buf + ASLOT * 8 + (size_t)(r * 512 + w * 64) * 8);
    }
}

template<int MODE>
__global__ __launch_bounds__(512, 4) void dist_mfma_kernel(
        const unsigned short* __restrict__ Asp,   // [n][128]
        const unsigned short* __restrict__ Bsp,   // [N][128]
        const float* __restrict__ x2,
        const float* __restrict__ y2,
        unsigned short* __restrict__ keyout,      // MODE 0: [n][N]
        const unsigned int* __restrict__ Tq,      // MODE 1
        unsigned int* __restrict__ cnt,           // MODE 1
        unsigned int* __restrict__ candbuf,       // MODE 1
        int N, int rowsM) {
    __shared__ __align__(16) unsigned short sh[2 * BUFELEM];   // 48 KB
    unsigned short* bufA = sh;
    unsigned short* bufB = sh + BUFELEM;

    const int nwg = (N / BN) * rowsM;
    const int cpx = nwg >> 3;
    const int bid = blockIdx.x;
    const int swz = (bid & 7) * cpx + (bid >> 3);
    const int col   = swz / rowsM;
    const int mrowi = swz - col * rowsM;
    const int nb = col * BN;
    const int mb = mrowi * BM;

    const int tid  = threadIdx.x;
    const int lane = tid & 63;
    const int w    = tid >> 6;
    const int wr   = w >> 2, wc = w & 3;   // 2 x 4 wave grid, 64x64 per wave

    f32x4 acc[4][4];
    #pragma unroll
    for (int i = 0; i < 4; ++i)
        #pragma unroll
        for (int j = 0; j < 4; ++j)
            acc[i][j] = (f32x4){0.f, 0.f, 0.f, 0.f};

    stage_slab(Asp, Bsp, bufA, mb, nb, 0, w, lane);

    const int c = lane >> 4;
    #pragma unroll
    for (int s = 0; s < NSLAB; ++s) {
        __syncthreads();                   // drains stage(s) + compute(s-1) done
        unsigned short* cur = (s & 1) ? bufB : bufA;
        unsigned short* nxt = (s & 1) ? bufA : bufB;
        if (s + 1 < NSLAB)
            stage_slab(Asp, Bsp, nxt, mb, nb, (s + 1) * BKS, w, lane);  // DMA overlaps MFMA
        const unsigned short* Acur = cur;
        const unsigned short* Bcur = cur + ASLOT * 8;
        half8 af[4], bf[4];
        #pragma unroll
        for (int f = 0; f < 4; ++f) {
            int m  = wr * 64 + f * 16 + (lane & 15);
            af[f] = lds_read_half8(Acur + (size_t)(m * 4 + (c ^ ((m >> 1) & 3))) * 8);
            int nn = wc * 64 + f * 16 + (lane & 15);
            bf[f] = lds_read_half8(Bcur + (size_t)(nn * 4 + (c ^ ((nn >> 1) & 3))) * 8);
        }
        __builtin_amdgcn_s_setprio(1);
        #pragma unroll
        for (int i = 0; i < 4; ++i)
            #pragma unroll
            for (int j = 0; j < 4; ++j)
                acc[i][j] = __builtin_amdgcn_mfma_f32_16x16x32_f16(af[i], bf[j], acc[i][j], 0, 0, 0);
        __builtin_amdgcn_s_setprio(0);
    }

    __syncthreads();    // all LDS reads done before epilogue reuse

    float x2v[16];
    unsigned int Trow[16];
    #pragma unroll
    for (int fi = 0; fi < 4; ++fi)
        #pragma unroll
        for (int r = 0; r < 4; ++r) {
            int ml = wr * 64 + fi * 16 + (lane >> 4) * 4 + r;
            x2v[fi * 4 + r] = x2[mb + ml];
            if (MODE == 1) Trow[fi * 4 + r] = Tq[mb + ml] + 4u;   // window completeness
        }

    if (MODE == 0) {
        #pragma unroll
        for (int fj = 0; fj < 4; ++fj) {
            float yv = y2[nb + wc * 64 + fj * 16 + (lane & 15)];
            #pragma unroll
            for (int fi = 0; fi < 4; ++fi) {
                #pragma unroll
                for (int r = 0; r < 4; ++r) {
                    float d = fmaf(-2.0f, acc[fi][fj][r], SCALE2 * (x2v[fi * 4 + r] + yv));
                    d = fmaxf(d, 0.0f);
                    int m  = mb + wr * 64 + fi * 16 + (lane >> 4) * 4 + r;
                    int nn = nb + wc * 64 + fj * 16 + (lane & 15);
                    keyout[(size_t)m * N + nn] = (unsigned short)(__float_as_uint(d) >> 15);
                }
            }
        }
    } else {
        unsigned int* rowcnt  = (unsigned int*)sh;             // 128
        unsigned int* slots   = rowcnt + 128;                  // 128*32
        unsigned int* rowbase = slots + 128 * 32;              // 128
        for (int i = tid; i < 128; i += 512) rowcnt[i] = 0;
        __syncthreads();
        #pragma unroll
        for (int fj = 0; fj < 4; ++fj) {
            float yv = y2[nb + wc * 64 + fj * 16 + (lane & 15)];
            #pragma unroll
            for (int fi = 0; fi < 4; ++fi) {
                #pragma unroll
                for (int r = 0; r < 4; ++r) {
                    float d = fmaf(-2.0f, acc[fi][fj][r], SCALE2 * (x2v[fi * 4 + r] + yv));
                    d = fmaxf(d, 0.0f);
                    unsigned int key = __float_as_uint(d) >> 15;
                    if (key < Trow[fi * 4 + r]) {
                        int ml = wr * 64 + fi * 16 + (lane >> 4) * 4 + r;
                        int cl = wc * 64 + fj * 16 + (lane & 15);     // 0..255
                        unsigned int p = atomicAdd(&rowcnt[ml], 1u);
                        if (p < 32) {
                            slots[ml * 32 + p] = (key << 16) | (unsigned int)cl;
                        } else {   // rare spill: direct global append
                            unsigned int b = atomicAdd(&cnt[mb + ml], 1u);
                            if (b < SEL_CAP)
                                candbuf[(size_t)(mb + ml) * SEL_CAP + b] =
                                    (key << 16) | (unsigned int)(nb + cl);
                        }
                    }
                }
            }
        }
        __syncthreads();
        int ml2 = tid >> 2;                  // 512 threads -> 4 per row
        unsigned int cc = rowcnt[ml2]; if (cc > 32) cc = 32;
        if ((tid & 3) == 0) rowbase[ml2] = atomicAdd(&cnt[mb + ml2], cc);
        __syncthreads();
        unsigned int bse = rowbase[ml2];
        for (unsigned int i = tid & 3; i < cc; i += 4) {
            unsigned int e = slots[ml2 * 32 + i];
            unsigned int dst = bse + i;
            if (dst < SEL_CAP)
                candbuf[(size_t)(mb + ml2) * SEL_CAP + dst] =
                    (e & 0xFFFF0000u) | (unsigned int)(nb + (e & 0xFFu));
        }
    }
}

// ---------------- per-query threshold from sample keys (also zeroes cnt) ----------------
__global__ __launch_bounds__(256) void tsel_kernel(const unsigned short* __restrict__ skey,
                                                   unsigned int* __restrict__ Tq,
                                                   unsigned int* __restrict__ cnt) {
    __shared__ unsigned int hist[256];
    __shared__ unsigned int binsel, cumsel, losel;
    const int tid = threadIdx.x;
    const int q   = blockIdx.x;
    if (tid == 0) cnt[q] = 0;
    uint2 v = ((const uint2*)(skey + (size_t)q * SAMPLE_N))[tid];   // 4 keys
    unsigned int k0 = v.x & 0xFFFFu, k1 = v.x >> 16;
    unsigned int k2 = v.y & 0xFFFFu, k3 = v.y >> 16;

    hist[tid] = 0;
    __syncthreads();
    atomicAdd(&hist[k0 >> 8], 1u); atomicAdd(&hist[k1 >> 8], 1u);
    atomicAdd(&hist[k2 >> 8], 1u); atomicAdd(&hist[k3 >> 8], 1u);
    __syncthreads();
    if (tid == 0) {
        unsigned int cum = 0;
        for (int b = 0; b < 256; ++b) {
            unsigned int h = hist[b];
            if (cum + h >= SAMPLE_R) { binsel = (unsigned int)b; cumsel = cum; break; }
            cum += h;
        }
    }
    __syncthreads();
    unsigned int bsel = binsel, need = SAMPLE_R - cumsel;
    hist[tid] = 0;
    __syncthreads();
    if ((k0 >> 8) == bsel) atomicAdd(&hist[k0 & 0xFFu], 1u);
    if ((k1 >> 8) == bsel) atomicAdd(&hist[k1 & 0xFFu], 1u);
    if ((k2 >> 8) == bsel) atomicAdd(&hist[k2 & 0xFFu], 1u);
    if ((k3 >> 8) == bsel) atomicAdd(&hist[k3 & 0xFFu], 1u);
    __syncthreads();
    if (tid == 0) {
        unsigned int cum = 0;
        for (int b = 0; b < 256; ++b) {
            cum += hist[b];
            if (cum >= need) { losel = (unsigned int)b; break; }
        }
        Tq[q] = ((bsel << 8) | losel) + 1u;
    }
}

// ---------------- selection + vote (v10): shfl 3-probe tau + wave-parallel f64 window ----------------
#define SEL_T3  512
#define NW      (SEL_T3 / 64)       // 8 waves
#define TIE_CAP 1024

__global__ __launch_bounds__(SEL_T3, 4) void select10_kernel(
        const unsigned int* __restrict__ cnt,
        const unsigned int* __restrict__ candbuf,
        const float* __restrict__ labels,
        const float* __restrict__ Q, const float* __restrict__ Dta,
        int* __restrict__ out, int n_total, int out_size) {
    __shared__ unsigned int cand[SEL_CAP];    // 32 KB
    __shared__ double       cval[TIE_CAP];    // 8 KB
    __shared__ unsigned int ckey[TIE_CAP];    // 4 KB
    __shared__ unsigned int red[2][3][NW];
    __shared__ unsigned int votes_sh, tcnt, base_sh;

    const int tid  = threadIdx.x;
    const int lane = tid & 63;
    const int wid  = tid >> 6;
    const int q    = blockIdx.x;

    unsigned int mraw = cnt[q];
    const int m = (int)(mraw < SEL_CAP ? mraw : SEL_CAP);
    for (int i = tid; i < m; i += SEL_T3) cand[i] = candbuf[(size_t)q * SEL_CAP + i];
    if (tid == 0) { votes_sh = 0; tcnt = 0; base_sh = 0; }
    __syncthreads();

    // ---- 8-pass 3-probe binary search for tau (key16 of the 128th smallest) ----
    uint32_t lo = 0, hi = 65536;
    #pragma unroll 1
    for (int pass = 0; pass < 8; ++pass) {
        uint32_t qs = (hi - lo) >> 2;
        uint32_t p1 = lo + qs, p2 = p1 + qs, p3 = p2 + qs;
        uint32_t c1 = 0, c2 = 0, c3 = 0;
        #pragma unroll
        for (int p = 0; p < SEL_CAP / SEL_T3; ++p) {
            int idx = p * SEL_T3 + tid;
            if (idx < m) {
                uint32_t k = cand[idx] >> 16;
                c1 += (k < p1); c2 += (k < p2); c3 += (k < p3);
            }
        }
        #pragma unroll
        for (int off = 32; off > 0; off >>= 1) {
            c1 += __shfl_down(c1, off, 64);
            c2 += __shfl_down(c2, off, 64);
            c3 += __shfl_down(c3, off, 64);
        }
        int bsel = pass & 1;
        if (lane == 0) {
            red[bsel][0][wid] = c1; red[bsel][1][wid] = c2; red[bsel][2][wid] = c3;
        }
        __syncthreads();
        uint32_t t1 = 0, t2 = 0, t3 = 0;
        #pragma unroll
        for (int ww = 0; ww < NW; ++ww) {
            t1 += red[bsel][0][ww]; t2 += red[bsel][1][ww]; t3 += red[bsel][2][ww];
        }
        if      (t1 >= TOPK) { hi = p1; }
        else if (t2 >= TOPK) { lo = p1; hi = p2; }
        else if (t3 >= TOPK) { lo = p2; hi = p3; }
        else                 { lo = p3; }
    }
    const int tau = (int)lo;
    int wlo = tau - 3; if (wlo < 0) wlo = 0;    // certain only outside [tau-3, tau+2]
    const int whi = tau + 2;

    // ---- pass: votes + base below window; gather window entries (index+label) ----
    unsigned int votes = 0, basec = 0;
    for (int i = tid; i < m; i += SEL_T3) {
        unsigned int u = cand[i];
        int          k = (int)(u >> 16);
        unsigned int j = u & 0xFFFFu;
        if (k < wlo) {
            basec++;
            votes += (labels[j] > 0.5f) ? 1u : 0u;
        } else if (k <= whi) {
            unsigned int lab = (labels[j] > 0.5f) ? 0x80000000u : 0u;
            unsigned int e = atomicAdd(&tcnt, 1u);
            if (e < TIE_CAP) ckey[e] = j | lab;
        }
    }
    #pragma unroll
    for (int off = 32; off > 0; off >>= 1) {
        votes += __shfl_down(votes, off, 64);
        basec += __shfl_down(basec, off, 64);
    }
    if (lane == 0) {
        if (votes) atomicAdd(&votes_sh, votes);
        if (basec) atomicAdd(&base_sh, basec);
    }
    __syncthreads();

    // ---- wave-parallel exact f64 distances for window entries ----
    unsigned int mt = tcnt; if (mt > TIE_CAP) mt = TIE_CAP;
    const float* qp = Q + (size_t)q * D_FEAT;
    for (unsigned int e = wid; e < mt; e += NW) {
        unsigned int j = ckey[e] & 0xFFFFu;
        const float* dp = Dta + (size_t)j * D_FEAT;
        double s = 0.0;
        #pragma unroll
        for (int k2 = 0; k2 < 2; ++k2) {
            int idx = lane + k2 * 64;
            double df = (double)qp[idx] - (double)dp[idx];
            s = fma(df, df, s);
        }
        #pragma unroll
        for (int off = 32; off > 0; off >>= 1) s += __shfl_down(s, off, 64);
        if (lane == 0) cval[e] = s;
    }
    __syncthreads();

    // ---- exact ranking of window; take first t_take ----
    const unsigned int t_take = TOPK - base_sh;    // base < 128 by tau construction
    for (unsigned int e = tid; e < mt; e += SEL_T3) {
        double       ve = cval[e];
        unsigned int ke = ckey[e];
        unsigned int ie = ke & 0x7FFFFFFFu;
        unsigned int rank = 0;
        for (unsigned int f = 0; f < mt; ++f) {
            double       vf = cval[f];
            unsigned int jf = ckey[f] & 0x7FFFFFFFu;
            rank += (vf < ve || (vf == ve && jf < ie)) ? 1u : 0u;
        }
        if (rank < t_take && (ke & 0x80000000u)) atomicAdd(&votes_sh, 1u);
    }
    __syncthreads();

    if (tid == 0) {
        out[q] = (votes_sh > TOPK / 2) ? 1 : 0;     // 64/64 tie -> class 0
        if (q == 0 && out_size > n_total) out[n_total] = 0;
    }
}

// ---------------- host ----------------
extern "C" void kernel_launch(void* const* d_in, const int* in_sizes, int n_in,
                              void* d_out, int out_size, void* d_ws, size_t ws_size,
                              hipStream_t stream) {
    const float* Q   = (const float*)d_in[0];
    const float* Dta = (const float*)d_in[1];
    const float* L   = (const float*)d_in[2];
    const int n = in_sizes[0] / D_FEAT;    // 2048
    const int N = in_sizes[1] / D_FEAT;    // 65536
    int* out = (int*)d_out;

    char* ws = (char*)d_ws;
    size_t off = 0;
    float* y2 = (float*)(ws + off);          off += (((size_t)N * 4) + 255) & ~(size_t)255;
    float* x2 = (float*)(ws + off);          off += (((size_t)n * 4) + 255) & ~(size_t)255;
    unsigned short* Asp = (unsigned short*)(ws + off); off += (((size_t)n * KSPLIT * 2) + 255) & ~(size_t)255;
    unsigned short* Bsp = (unsigned short*)(ws + off); off += (((size_t)N * KSPLIT * 2) + 255) & ~(size_t)255;
    unsigned short* skey = (unsigned short*)(ws + off); off += (((size_t)n * SAMPLE_N * 2) + 255) & ~(size_t)255;
    unsigned int* Tq  = (unsigned int*)(ws + off);    off += (((size_t)n * 4) + 255) & ~(size_t)255;
    unsigned int* cnt = (unsigned int*)(ws + off);    off += (((size_t)n * 4) + 255) & ~(size_t)255;
    unsigned int* candbuf = (unsigned int*)(ws + off);   // n * SEL_CAP * 4 = 64 MB

    // fused sqnorm + h-split, grid-stride
    prep_kernel<<<dim3(2048), dim3(256), 0, stream>>>(Q, Dta, Asp, Bsp, x2, y2, n, N);

    const int rowsM = n / BM;                         // 16
    dist_mfma_kernel<0><<<dim3((SAMPLE_N / BN) * rowsM), dim3(512), 0, stream>>>(
        Asp, Bsp, x2, y2, skey, nullptr, nullptr, nullptr, SAMPLE_N, rowsM);
    tsel_kernel<<<dim3(n), dim3(256), 0, stream>>>(skey, Tq, cnt);
    dist_mfma_kernel<1><<<dim3((N / BN) * rowsM), dim3(512), 0, stream>>>(
        Asp, Bsp, x2, y2, nullptr, Tq, cnt, candbuf, N, rowsM);
    select10_kernel<<<dim3(n), dim3(SEL_T3), 0, stream>>>(cnt, candbuf, L, Q, Dta, out, n, out_size);
}